// Round 4
// baseline (2408.969 us; speedup 1.0000x reference)
//
#include <hip/hip_runtime.h>
#include <cstdint>
#include <cstddef>

// ---------------- problem constants ----------------
#define VOCAB 32000
#define EMB   256
#define HID   1024
#define NB    16      // batch
#define SS    512     // seq
#define MTOK  (NB*SS) // 8192 tokens
#define KDIM  1024    // NM1*EMB = HID
#define NCHUNK 500    // 32000 / 64 cols per wave-chunk
#define PSTRIDE 512   // padded chunk stride

typedef __bf16 bf16_t;
typedef bf16_t bf16x8 __attribute__((ext_vector_type(8)));
typedef float  f32x4  __attribute__((ext_vector_type(4)));
typedef float  f32x16 __attribute__((ext_vector_type(16)));
typedef int    i32x4  __attribute__((ext_vector_type(4)));
typedef int    i32x8  __attribute__((ext_vector_type(8)));

__device__ __forceinline__ unsigned short f32_to_bf16(float f) {
  union { float f; unsigned int u; } v; v.f = f;
  unsigned int u = v.u;
  unsigned int r = (u + 0x7FFFu + ((u >> 16) & 1u)) >> 16; // RNE
  return (unsigned short)r;
}

// f32 -> OCP e4m3fn, RNE, software (input assumed |x| <= 448)
__device__ __forceinline__ uint8_t f32_to_e4m3(float x) {
  union { float f; uint32_t u; } v; v.f = x;
  uint32_t s = (v.u >> 24) & 0x80u;
  int e = (int)((v.u >> 23) & 0xffu) - 127;
  uint32_t m = v.u & 0x7fffffu;
  if (e < -9) return (uint8_t)s;                  // -> 0
  if (e >= -6) {                                  // normal range
    uint32_t keep = m >> 20;
    uint32_t rest = m & 0xfffffu;
    keep += (rest > 0x80000u) || (rest == 0x80000u && (keep & 1u));
    if (keep == 8u) { keep = 0u; e += 1; }
    int code = ((e + 7) << 3) | (int)keep;
    if (code >= 0x7f) code = 0x7e;                // clamp to 448 (avoid NaN)
    return (uint8_t)(s | (uint32_t)code);
  }
  // subnormal: k = round(x * 512) in [0,8)
  uint32_t full = 0x800000u | m;
  int shift = 20 + (-6 - e);                      // 21..23
  uint32_t keep = full >> shift;
  uint32_t rest = full & ((1u << shift) - 1u);
  uint32_t half = 1u << (shift - 1);
  keep += (rest > half) || (rest == half && (keep & 1u));
  if (keep >= 8u) return (uint8_t)(s | 0x08u);    // rounds to min normal
  return (uint8_t)(s | keep);
}

__device__ __forceinline__ void gload_lds16(const void* gsrc, void* ldst) {
  __builtin_amdgcn_global_load_lds(
      (__attribute__((address_space(1))) void*)gsrc,
      (__attribute__((address_space(3))) void*)ldst,
      16, 0, 0);
}

// ---------------- transpose + convert: in[R][C] f32 -> out[C][R] ----------------
__global__ void k_transpose_bf16(const float* __restrict__ in,
                                 unsigned short* __restrict__ out,
                                 int R, int C) {
  __shared__ float tile[32][33];
  int bc = blockIdx.x * 32, br = blockIdx.y * 32;
  int tx = threadIdx.x & 31, ty = threadIdx.x >> 5;
#pragma unroll
  for (int i = 0; i < 32; i += 8)
    tile[ty + i][tx] = in[(size_t)(br + ty + i) * C + (bc + tx)];
  __syncthreads();
#pragma unroll
  for (int i = 0; i < 32; i += 8)
    out[(size_t)(bc + ty + i) * R + (br + tx)] = f32_to_bf16(tile[tx][ty + i]);
}

__global__ void k_transpose_fp8(const float* __restrict__ in,
                                uint8_t* __restrict__ out,
                                int R, int C) {
  __shared__ float tile[32][33];
  int bc = blockIdx.x * 32, br = blockIdx.y * 32;
  int tx = threadIdx.x & 31, ty = threadIdx.x >> 5;
#pragma unroll
  for (int i = 0; i < 32; i += 8)
    tile[ty + i][tx] = in[(size_t)(br + ty + i) * C + (bc + tx)];
  __syncthreads();
#pragma unroll
  for (int i = 0; i < 32; i += 8)
    out[(size_t)(bc + ty + i) * R + (br + tx)] = f32_to_e4m3(tile[tx][ty + i] * 16.0f);
}

// ---------------- embedding gather ----------------
__global__ void k_gather_e(const int* __restrict__ text,
                           const float* __restrict__ embed,
                           unsigned short* __restrict__ E) {
  int t = blockIdx.x;
  int b = t >> 9, s = t & 511;
  int d = threadIdx.x; // 0..255
#pragma unroll
  for (int j = 0; j < 4; ++j) {
    int sidx = s + j - 4;
    int tok = (sidx >= 0) ? text[b * SS + sidx] : 0;
    float val = (tok != 0) ? embed[(size_t)tok * EMB + d] : 0.0f;
    E[(size_t)t * KDIM + j * EMB + d] = f32_to_bf16(val);
  }
}

// ---------------- FFN GEMM (128x128 tile, relu+bias; OUTQ=1 -> fp8 x16) ----------------
template<int OUTQ>
__global__ __launch_bounds__(256)
void k_gemm_ffn(const unsigned short* __restrict__ A,
                const unsigned short* __restrict__ Bt,
                const float* __restrict__ bias,
                void* __restrict__ Hout, int N) {
  __shared__ unsigned short As[128 * 32];
  __shared__ unsigned short Bs[128 * 32];
  const int tid  = threadIdx.x;
  const int bn   = blockIdx.x, bm = blockIdx.y;
  const int lane = tid & 63, wid = tid >> 6;
  const int wm = wid >> 1, wn = wid & 1;
  const int g = lane >> 4, c = lane & 15;

  f32x4 acc[4][4];
#pragma unroll
  for (int m = 0; m < 4; ++m)
#pragma unroll
    for (int n = 0; n < 4; ++n) { f32x4 z = {0.f, 0.f, 0.f, 0.f}; acc[m][n] = z; }

  const int arow = tid >> 2;
  const int slotb = ((tid & 3) ^ ((tid >> 3) & 3)) * 16;
  const char* gA0 = (const char*)A + ((size_t)(bm * 128 + arow) * KDIM) * 2 + slotb;
  const char* gA1 = gA0 + (size_t)64 * KDIM * 2;
  const char* gB0 = (const char*)Bt + ((size_t)(bn * 128 + arow) * KDIM) * 2 + slotb;
  const char* gB1 = gB0 + (size_t)64 * KDIM * 2;
  char* lA = (char*)As + tid * 16;
  char* lB = (char*)Bs + tid * 16;

  const int rs = (g ^ ((c >> 1) & 3)) * 8;

  for (int kt = 0; kt < KDIM / 32; ++kt) {
    const int kb = kt * 64;
    gload_lds16(gA0 + kb, lA);
    gload_lds16(gA1 + kb, lA + 4096);
    gload_lds16(gB0 + kb, lB);
    gload_lds16(gB1 + kb, lB + 4096);
    __syncthreads();

    bf16x8 af[4], bf[4];
#pragma unroll
    for (int m = 0; m < 4; ++m)
      af[m] = *(const bf16x8*)&As[(wm * 64 + m * 16 + c) * 32 + rs];
#pragma unroll
    for (int n = 0; n < 4; ++n)
      bf[n] = *(const bf16x8*)&Bs[(wn * 64 + n * 16 + c) * 32 + rs];
#pragma unroll
    for (int m = 0; m < 4; ++m)
#pragma unroll
      for (int n = 0; n < 4; ++n)
        acc[m][n] = __builtin_amdgcn_mfma_f32_16x16x32_bf16(af[m], bf[n], acc[m][n], 0, 0, 0);
    __syncthreads();
  }

#pragma unroll
  for (int n = 0; n < 4; ++n) {
    int colg = bn * 128 + wn * 64 + n * 16 + c;
    float bv = bias[colg];
#pragma unroll
    for (int m = 0; m < 4; ++m)
#pragma unroll
      for (int j = 0; j < 4; ++j) {
        int rowg = bm * 128 + wm * 64 + m * 16 + g * 4 + j;
        float v = acc[m][n][j] + bv;
        v = v > 0.f ? v : 0.f;
        if constexpr (OUTQ == 0)
          ((unsigned short*)Hout)[(size_t)rowg * N + colg] = f32_to_bf16(v);
        else
          ((uint8_t*)Hout)[(size_t)rowg * N + colg] = f32_to_e4m3(v * 16.0f);
      }
  }
}

// ---------------- vocab GEMM: MX-fp8, 256x128 tile, BK=64, 4 waves ----------------
// A/B pre-scaled by 2^4 at conversion; MFMA scale operands = 2^-4 each (e8m0 byte 123).
// LDS [rows][64]B, quad-XOR swizzle q' = q ^ ((row>>1)&3): conflict-free b128 reads.
__global__ __launch_bounds__(256, 2)
void k_gemm_vocab_mx(const uint8_t* __restrict__ Aq,   // [MTOK][KDIM] fp8 (x16)
                     const uint8_t* __restrict__ Bq,   // [VOCAB][KDIM] fp8 (x16)
                     const float* __restrict__ bias,
                     float* __restrict__ pmax, float* __restrict__ psum,
                     float* __restrict__ tlog, const int* __restrict__ target) {
  __shared__ uint8_t As[256 * 64];  // 16 KB
  __shared__ uint8_t Bs[128 * 64];  //  8 KB
  const int tid  = threadIdx.x;
  const int lane = tid & 63, wid = tid >> 6;   // 4 waves
  const int wm = wid >> 1, wn = wid & 1;       // 2(M) x 2(N); per-wave out 128x64
  const int lr = lane & 31, kb = lane >> 5;

  // XCD-chunked swizzle; grid = 8000 = 32(bm) x 250(bn)
  const int o   = blockIdx.x;
  const int xcd = o & 7, idx = o >> 3;         // idx 0..999
  const int bm  = xcd * 4 + (idx & 3);         // 0..31
  const int bn  = idx >> 2;                    // 0..249

  f32x16 acc[4][2];
#pragma unroll
  for (int m = 0; m < 4; ++m)
#pragma unroll
    for (int n = 0; n < 2; ++n)
#pragma unroll
      for (int e = 0; e < 16; ++e) acc[m][n][e] = 0.f;

  // staging: thread t -> row (t>>2)+64h, LDS quad t&3; source quad (t&3)^((row>>1)&3)
  const int srow = tid >> 2, sq = tid & 3;
  const int gq = sq ^ ((srow >> 1) & 3);       // invariant under row+=64
  const uint8_t* gA = Aq + (size_t)(bm * 256 + srow) * KDIM + gq * 16;
  const uint8_t* gB = Bq + (size_t)(bn * 128 + srow) * KDIM + gq * 16;
  uint8_t* lA = As + tid * 16;
  uint8_t* lB = Bs + tid * 16;

  const int swz = (lr >> 1) & 3;

  for (int kt = 0; kt < KDIM / 64; ++kt) {
    const size_t ko = (size_t)kt * 64;
#pragma unroll
    for (int h = 0; h < 4; ++h)
      gload_lds16(gA + ko + (size_t)h * 64 * KDIM, lA + h * 4096);
#pragma unroll
    for (int h = 0; h < 2; ++h)
      gload_lds16(gB + ko + (size_t)h * 64 * KDIM, lB + h * 4096);
    __syncthreads();

    i32x8 a[4], b[2];
#pragma unroll
    for (int m = 0; m < 4; ++m) {
      const uint8_t* base = As + (wm * 128 + m * 32 + lr) * 64;
      i32x4 lo = *(const i32x4*)(base + (((kb << 1) | 0) ^ swz) * 16);
      i32x4 hi = *(const i32x4*)(base + (((kb << 1) | 1) ^ swz) * 16);
      a[m] = __builtin_shufflevector(lo, hi, 0, 1, 2, 3, 4, 5, 6, 7);
    }
#pragma unroll
    for (int n = 0; n < 2; ++n) {
      const uint8_t* base = Bs + (wn * 64 + n * 32 + lr) * 64;
      i32x4 lo = *(const i32x4*)(base + (((kb << 1) | 0) ^ swz) * 16);
      i32x4 hi = *(const i32x4*)(base + (((kb << 1) | 1) ^ swz) * 16);
      b[n] = __builtin_shufflevector(lo, hi, 0, 1, 2, 3, 4, 5, 6, 7);
    }
#pragma unroll
    for (int m = 0; m < 4; ++m)
#pragma unroll
      for (int n = 0; n < 2; ++n)
        acc[m][n] = __builtin_amdgcn_mfma_scale_f32_32x32x64_f8f6f4(
            a[m], b[n], acc[m][n], 0 /*cbsz=fp8*/, 0 /*blgp=fp8*/,
            0, 123 /*A scale 2^-4*/, 0, 123 /*B scale 2^-4*/);
    __syncthreads();
  }

  // ---- epilogue: fused softmax stats per 64-col wave chunk ----
  // C/D 32x32 layout: col = lane&31, row = (reg&3) + 8*(reg>>2) + 4*(lane>>5)
  const int chunk = bn * 2 + wn;
  const int colbase = bn * 128 + wn * 64;
  float bov0 = bias[colbase + lr];
  float bov1 = bias[colbase + 32 + lr];
#pragma unroll
  for (int m = 0; m < 4; ++m) {
#pragma unroll
    for (int reg = 0; reg < 16; ++reg) {
      int rowg = bm * 256 + wm * 128 + m * 32 + (reg & 3) + 8 * (reg >> 2) + 4 * kb;
      float v0 = acc[m][0][reg] + bov0;
      float v1 = acc[m][1][reg] + bov1;
      float mv = fmaxf(v0, v1);
#pragma unroll
      for (int sft = 1; sft < 32; sft <<= 1) mv = fmaxf(mv, __shfl_xor(mv, sft));
      float se = __expf(v0 - mv) + __expf(v1 - mv);
#pragma unroll
      for (int sft = 1; sft < 32; sft <<= 1) se += __shfl_xor(se, sft);
      if (lr == 0) {
        pmax[(size_t)rowg * PSTRIDE + chunk] = mv;
        psum[(size_t)rowg * PSTRIDE + chunk] = se;
      }
      int cw = target[rowg] - colbase;
      if (cw >= 0 && cw < 64 && lr == (cw & 31)) {
        tlog[rowg] = (cw < 32) ? v0 : v1;
      }
    }
  }
}

// ---------------- combine per-chunk stats -> nll per row ----------------
__global__ void k_reduce_nll(const float* __restrict__ pmax,
                             const float* __restrict__ psum,
                             const float* __restrict__ tlog,
                             float* __restrict__ nll) {
  int row = blockIdx.x;
  int lane = threadIdx.x; // 64
  float M = -1e30f;
  for (int ch = lane; ch < NCHUNK; ch += 64) M = fmaxf(M, pmax[(size_t)row * PSTRIDE + ch]);
#pragma unroll
  for (int s = 1; s < 64; s <<= 1) M = fmaxf(M, __shfl_xor(M, s));
  float L = 0.f;
  for (int ch = lane; ch < NCHUNK; ch += 64)
    L += __expf(pmax[(size_t)row * PSTRIDE + ch] - M) * psum[(size_t)row * PSTRIDE + ch];
#pragma unroll
  for (int s = 1; s < 64; s <<= 1) L += __shfl_xor(L, s);
  if (lane == 0) nll[row] = -(tlog[row] - M - logf(L));
}

// ---------------- masked per-step mean -> scalar loss ----------------
__global__ void k_loss(const int* __restrict__ target,
                       const float* __restrict__ nll,
                       float* __restrict__ out) {
  __shared__ float red[SS];
  int s = threadIdx.x; // 512
  float sl = 0.f, cnt = 0.f;
#pragma unroll
  for (int b = 0; b < NB; ++b) {
    int idx = b * SS + s;
    if (target[idx] != 0) { sl += nll[idx]; cnt += 1.f; }
  }
  red[s] = sl / fmaxf(cnt, 1.f);
  __syncthreads();
  for (int st = 256; st > 0; st >>= 1) {
    if (s < st) red[s] += red[s + st];
    __syncthreads();
  }
  if (s == 0) out[0] = red[0] / (float)SS;
}

// ---------------- launch ----------------
extern "C" void kernel_launch(void* const* d_in, const int* in_sizes, int n_in,
                              void* d_out, int out_size, void* d_ws, size_t ws_size,
                              hipStream_t stream) {
  (void)in_sizes; (void)n_in; (void)out_size; (void)ws_size;
  const int*   text   = (const int*)d_in[0];
  const int*   target = (const int*)d_in[1];
  const float* embed  = (const float*)d_in[2];
  const float* W1     = (const float*)d_in[3];
  const float* b1     = (const float*)d_in[4];
  const float* W2     = (const float*)d_in[5];
  const float* b2     = (const float*)d_in[6];
  const float* Wo     = (const float*)d_in[7];
  const float* bo     = (const float*)d_in[8];
  float* out = (float*)d_out;
  char* ws = (char*)d_ws;

  const size_t SZ_E = (size_t)MTOK * KDIM * 2;          // 16.78 MB (bf16)
  unsigned short* E   = (unsigned short*)(ws);
  unsigned short* H1  = (unsigned short*)(ws + SZ_E);
  uint8_t*        H2Q = (uint8_t*)(ws + 2 * SZ_E);      // fp8, 8.39 MB
  char* p = ws + 2 * SZ_E + (size_t)MTOK * KDIM;
  unsigned short* W1t = (unsigned short*)p;  p += (size_t)HID * HID * 2;
  unsigned short* W2t = (unsigned short*)p;  p += (size_t)HID * HID * 2;
  uint8_t*        WoQ = (uint8_t*)p;         p += (size_t)VOCAB * HID;   // fp8, 32.77 MB
  float* tlog = (float*)p;                   p += (size_t)MTOK * 4;
  float* nll  = (float*)p;
  float* pmax = (float*)E;   // E dead after GEMM1
  float* psum = (float*)H1;  // H1 dead after GEMM2

  k_transpose_bf16<<<dim3(HID / 32, HID / 32), 256, 0, stream>>>(W1, W1t, HID, HID);
  k_transpose_bf16<<<dim3(HID / 32, HID / 32), 256, 0, stream>>>(W2, W2t, HID, HID);
  k_transpose_fp8 <<<dim3(VOCAB / 32, HID / 32), 256, 0, stream>>>(Wo, WoQ, HID, VOCAB);
  k_gather_e<<<MTOK, 256, 0, stream>>>(text, embed, E);

  k_gemm_ffn<0><<<dim3(HID / 128, MTOK / 128), 256, 0, stream>>>(E, W1t, b1, (void*)H1, HID);
  k_gemm_ffn<1><<<dim3(HID / 128, MTOK / 128), 256, 0, stream>>>(H1, W2t, b2, (void*)H2Q, HID);

  k_gemm_vocab_mx<<<dim3((MTOK / 256) * (VOCAB / 128)), 256, 0, stream>>>(
      H2Q, WoQ, bo, pmax, psum, tlog, target);

  k_reduce_nll<<<MTOK, 64, 0, stream>>>(pmax, psum, tlog, nll);
  k_loss<<<1, SS, 0, stream>>>(target, nll, out);
}

// Round 5
// 1922.899 us; speedup vs baseline: 1.2528x; 1.2528x over previous
//
#include <hip/hip_runtime.h>
#include <cstdint>
#include <cstddef>

// ---------------- problem constants ----------------
#define VOCAB 32000
#define EMB   256
#define HID   1024
#define NB    16      // batch
#define SS    512     // seq
#define MTOK  (NB*SS) // 8192 tokens
#define KDIM  1024    // NM1*EMB = HID
#define NCHUNK 500    // 32000 / 64 cols per wave-chunk
#define PSTRIDE 512   // padded chunk stride

typedef __bf16 bf16_t;
typedef bf16_t bf16x8 __attribute__((ext_vector_type(8)));
typedef float  f32x4  __attribute__((ext_vector_type(4)));
typedef float  f32x16 __attribute__((ext_vector_type(16)));
typedef int    i32x4  __attribute__((ext_vector_type(4)));
typedef int    i32x8  __attribute__((ext_vector_type(8)));

__device__ __forceinline__ unsigned short f32_to_bf16(float f) {
  union { float f; unsigned int u; } v; v.f = f;
  unsigned int u = v.u;
  unsigned int r = (u + 0x7FFFu + ((u >> 16) & 1u)) >> 16; // RNE
  return (unsigned short)r;
}

// f32 -> OCP e4m3fn, RNE, software (input assumed |x| <= 448)
__device__ __forceinline__ uint8_t f32_to_e4m3(float x) {
  union { float f; uint32_t u; } v; v.f = x;
  uint32_t s = (v.u >> 24) & 0x80u;
  int e = (int)((v.u >> 23) & 0xffu) - 127;
  uint32_t m = v.u & 0x7fffffu;
  if (e < -9) return (uint8_t)s;                  // -> 0
  if (e >= -6) {                                  // normal range
    uint32_t keep = m >> 20;
    uint32_t rest = m & 0xfffffu;
    keep += (rest > 0x80000u) || (rest == 0x80000u && (keep & 1u));
    if (keep == 8u) { keep = 0u; e += 1; }
    int code = ((e + 7) << 3) | (int)keep;
    if (code >= 0x7f) code = 0x7e;                // clamp to 448 (avoid NaN)
    return (uint8_t)(s | (uint32_t)code);
  }
  // subnormal
  uint32_t full = 0x800000u | m;
  int shift = 20 + (-6 - e);                      // 21..23
  uint32_t keep = full >> shift;
  uint32_t rest = full & ((1u << shift) - 1u);
  uint32_t half = 1u << (shift - 1);
  keep += (rest > half) || (rest == half && (keep & 1u));
  if (keep >= 8u) return (uint8_t)(s | 0x08u);
  return (uint8_t)(s | keep);
}

__device__ __forceinline__ void gload_lds16(const void* gsrc, void* ldst) {
  __builtin_amdgcn_global_load_lds(
      (__attribute__((address_space(1))) void*)gsrc,
      (__attribute__((address_space(3))) void*)ldst,
      16, 0, 0);
}

// ---------------- transpose + convert: in[R][C] f32 -> out[C][R] ----------------
__global__ void k_transpose_bf16(const float* __restrict__ in,
                                 unsigned short* __restrict__ out,
                                 int R, int C) {
  __shared__ float tile[32][33];
  int bc = blockIdx.x * 32, br = blockIdx.y * 32;
  int tx = threadIdx.x & 31, ty = threadIdx.x >> 5;
#pragma unroll
  for (int i = 0; i < 32; i += 8)
    tile[ty + i][tx] = in[(size_t)(br + ty + i) * C + (bc + tx)];
  __syncthreads();
#pragma unroll
  for (int i = 0; i < 32; i += 8)
    out[(size_t)(bc + ty + i) * R + (br + tx)] = f32_to_bf16(tile[tx][ty + i]);
}

__global__ void k_transpose_fp8(const float* __restrict__ in,
                                uint8_t* __restrict__ out,
                                int R, int C) {
  __shared__ float tile[32][33];
  int bc = blockIdx.x * 32, br = blockIdx.y * 32;
  int tx = threadIdx.x & 31, ty = threadIdx.x >> 5;
#pragma unroll
  for (int i = 0; i < 32; i += 8)
    tile[ty + i][tx] = in[(size_t)(br + ty + i) * C + (bc + tx)];
  __syncthreads();
#pragma unroll
  for (int i = 0; i < 32; i += 8)
    out[(size_t)(bc + ty + i) * R + (br + tx)] = f32_to_e4m3(tile[tx][ty + i] * 16.0f);
}

// ---------------- embedding gather ----------------
__global__ void k_gather_e(const int* __restrict__ text,
                           const float* __restrict__ embed,
                           unsigned short* __restrict__ E) {
  int t = blockIdx.x;
  int b = t >> 9, s = t & 511;
  int d = threadIdx.x; // 0..255
#pragma unroll
  for (int j = 0; j < 4; ++j) {
    int sidx = s + j - 4;
    int tok = (sidx >= 0) ? text[b * SS + sidx] : 0;
    float val = (tok != 0) ? embed[(size_t)tok * EMB + d] : 0.0f;
    E[(size_t)t * KDIM + j * EMB + d] = f32_to_bf16(val);
  }
}

// ---------------- FFN GEMM (128x128 tile, relu+bias; OUTQ=1 -> fp8 x16) ----------------
template<int OUTQ>
__global__ __launch_bounds__(256)
void k_gemm_ffn(const unsigned short* __restrict__ A,
                const unsigned short* __restrict__ Bt,
                const float* __restrict__ bias,
                void* __restrict__ Hout, int N) {
  __shared__ unsigned short As[128 * 32];
  __shared__ unsigned short Bs[128 * 32];
  const int tid  = threadIdx.x;
  const int bn   = blockIdx.x, bm = blockIdx.y;
  const int lane = tid & 63, wid = tid >> 6;
  const int wm = wid >> 1, wn = wid & 1;
  const int g = lane >> 4, c = lane & 15;

  f32x4 acc[4][4];
#pragma unroll
  for (int m = 0; m < 4; ++m)
#pragma unroll
    for (int n = 0; n < 4; ++n) { f32x4 z = {0.f, 0.f, 0.f, 0.f}; acc[m][n] = z; }

  const int arow = tid >> 2;
  const int slotb = ((tid & 3) ^ ((tid >> 3) & 3)) * 16;
  const char* gA0 = (const char*)A + ((size_t)(bm * 128 + arow) * KDIM) * 2 + slotb;
  const char* gA1 = gA0 + (size_t)64 * KDIM * 2;
  const char* gB0 = (const char*)Bt + ((size_t)(bn * 128 + arow) * KDIM) * 2 + slotb;
  const char* gB1 = gB0 + (size_t)64 * KDIM * 2;
  char* lA = (char*)As + tid * 16;
  char* lB = (char*)Bs + tid * 16;

  const int rs = (g ^ ((c >> 1) & 3)) * 8;

  for (int kt = 0; kt < KDIM / 32; ++kt) {
    const int kb = kt * 64;
    gload_lds16(gA0 + kb, lA);
    gload_lds16(gA1 + kb, lA + 4096);
    gload_lds16(gB0 + kb, lB);
    gload_lds16(gB1 + kb, lB + 4096);
    __syncthreads();

    bf16x8 af[4], bf[4];
#pragma unroll
    for (int m = 0; m < 4; ++m)
      af[m] = *(const bf16x8*)&As[(wm * 64 + m * 16 + c) * 32 + rs];
#pragma unroll
    for (int n = 0; n < 4; ++n)
      bf[n] = *(const bf16x8*)&Bs[(wn * 64 + n * 16 + c) * 32 + rs];
#pragma unroll
    for (int m = 0; m < 4; ++m)
#pragma unroll
      for (int n = 0; n < 4; ++n)
        acc[m][n] = __builtin_amdgcn_mfma_f32_16x16x32_bf16(af[m], bf[n], acc[m][n], 0, 0, 0);
    __syncthreads();
  }

#pragma unroll
  for (int n = 0; n < 4; ++n) {
    int colg = bn * 128 + wn * 64 + n * 16 + c;
    float bv = bias[colg];
#pragma unroll
    for (int m = 0; m < 4; ++m)
#pragma unroll
      for (int j = 0; j < 4; ++j) {
        int rowg = bm * 128 + wm * 64 + m * 16 + g * 4 + j;
        float v = acc[m][n][j] + bv;
        v = v > 0.f ? v : 0.f;
        if constexpr (OUTQ == 0)
          ((unsigned short*)Hout)[(size_t)rowg * N + colg] = f32_to_bf16(v);
        else
          ((uint8_t*)Hout)[(size_t)rowg * N + colg] = f32_to_e4m3(v * 16.0f);
      }
  }
}

// ---------------- vocab GEMM: MX-fp8, 256x128 tile, BK=64, 4 waves, dbuf 2-phase ------
// A/B pre-scaled by 2^4; MFMA scale operands 2^-4 (e8m0 byte 123).
// NO min-occupancy launch bound: R4's (256,2) capped unified VGPR+AGPR at 256 ->
// acc(128 AGPR)+operands spilled to scratch (3.7 GB writes). Cap 512 removes spill.
__global__ __launch_bounds__(256)
void k_gemm_vocab_mx(const uint8_t* __restrict__ Aq,   // [MTOK][KDIM] fp8 (x16)
                     const uint8_t* __restrict__ Bq,   // [VOCAB][KDIM] fp8 (x16)
                     const float* __restrict__ bias,
                     float* __restrict__ pmax, float* __restrict__ psum,
                     float* __restrict__ tlog, const int* __restrict__ target) {
  __shared__ uint8_t As[2][256 * 64];  // 32 KB
  __shared__ uint8_t Bs[2][128 * 64];  // 16 KB
  const int tid  = threadIdx.x;
  const int lane = tid & 63, wid = tid >> 6;   // 4 waves
  const int wm = wid >> 1, wn = wid & 1;       // 2(M) x 2(N); per-wave out 128x64
  const int lr = lane & 31, kb = lane >> 5;

  // XCD-chunked swizzle; grid = 8000 = 32(bm) x 250(bn)
  const int o   = blockIdx.x;
  const int xcd = o & 7, idx = o >> 3;         // idx 0..999
  const int bm  = xcd * 4 + (idx & 3);         // 0..31
  const int bn  = idx >> 2;                    // 0..249

  f32x16 acc[4][2];
#pragma unroll
  for (int m = 0; m < 4; ++m)
#pragma unroll
    for (int n = 0; n < 2; ++n)
#pragma unroll
      for (int e = 0; e < 16; ++e) acc[m][n][e] = 0.f;

  // staging: thread t -> row (t>>2)+64h, LDS quad t&3; source quad (t&3)^((row>>1)&3)
  const int srow = tid >> 2, sq = tid & 3;
  const int gq = sq ^ ((srow >> 1) & 3);       // invariant under row+=64
  const uint8_t* gA = Aq + (size_t)(bm * 256 + srow) * KDIM + gq * 16;
  const uint8_t* gB = Bq + (size_t)(bn * 128 + srow) * KDIM + gq * 16;

#define STAGE(kt, d) do {                                                  \
    const size_t ko_ = (size_t)(kt) * 64;                                  \
    uint8_t* la_ = &As[d][0] + tid * 16;                                   \
    uint8_t* lb_ = &Bs[d][0] + tid * 16;                                   \
    _Pragma("unroll") for (int h = 0; h < 4; ++h)                          \
      gload_lds16(gA + ko_ + (size_t)h * 64 * KDIM, la_ + h * 4096);       \
    _Pragma("unroll") for (int h = 0; h < 2; ++h)                          \
      gload_lds16(gB + ko_ + (size_t)h * 64 * KDIM, lb_ + h * 4096);       \
  } while (0)

  const int swz = (lr >> 1) & 3;
  const int NT = KDIM / 64; // 16

  STAGE(0, 0);
  __syncthreads();  // drains vmcnt before barrier (compiler semantics)

  for (int kt = 0; kt < NT; ++kt) {
    const int cur = kt & 1;
    if (kt + 1 < NT) STAGE(kt + 1, cur ^ 1);   // prefetch into free buffer

    i32x8 a[4], b[2];
#pragma unroll
    for (int m = 0; m < 4; ++m) {
      const uint8_t* base = &As[cur][0] + (wm * 128 + m * 32 + lr) * 64;
      i32x4 lo = *(const i32x4*)(base + (((kb << 1) | 0) ^ swz) * 16);
      i32x4 hi = *(const i32x4*)(base + (((kb << 1) | 1) ^ swz) * 16);
      a[m] = __builtin_shufflevector(lo, hi, 0, 1, 2, 3, 4, 5, 6, 7);
    }
#pragma unroll
    for (int n = 0; n < 2; ++n) {
      const uint8_t* base = &Bs[cur][0] + (wn * 64 + n * 32 + lr) * 64;
      i32x4 lo = *(const i32x4*)(base + (((kb << 1) | 0) ^ swz) * 16);
      i32x4 hi = *(const i32x4*)(base + (((kb << 1) | 1) ^ swz) * 16);
      b[n] = __builtin_shufflevector(lo, hi, 0, 1, 2, 3, 4, 5, 6, 7);
    }
#pragma unroll
    for (int m = 0; m < 4; ++m)
#pragma unroll
      for (int n = 0; n < 2; ++n)
        acc[m][n] = __builtin_amdgcn_mfma_scale_f32_32x32x64_f8f6f4(
            a[m], b[n], acc[m][n], 0 /*cbsz=fp8*/, 0 /*blgp=fp8*/,
            0, 123 /*A scale 2^-4*/, 0, 123 /*B scale 2^-4*/);

    __syncthreads();  // reads done + prefetch landed (vmcnt drained)
  }
#undef STAGE

  // ---- epilogue: fused softmax stats per 64-col wave chunk ----
  // C/D 32x32 layout: col = lane&31, row = (reg&3) + 8*(reg>>2) + 4*(lane>>5)
  const int chunk = bn * 2 + wn;
  const int colbase = bn * 128 + wn * 64;
  float bov0 = bias[colbase + lr];
  float bov1 = bias[colbase + 32 + lr];
#pragma unroll
  for (int m = 0; m < 4; ++m) {
#pragma unroll
    for (int reg = 0; reg < 16; ++reg) {
      int rowg = bm * 256 + wm * 128 + m * 32 + (reg & 3) + 8 * (reg >> 2) + 4 * kb;
      float v0 = acc[m][0][reg] + bov0;
      float v1 = acc[m][1][reg] + bov1;
      float mv = fmaxf(v0, v1);
#pragma unroll
      for (int sft = 1; sft < 32; sft <<= 1) mv = fmaxf(mv, __shfl_xor(mv, sft));
      float se = __expf(v0 - mv) + __expf(v1 - mv);
#pragma unroll
      for (int sft = 1; sft < 32; sft <<= 1) se += __shfl_xor(se, sft);
      if (lr == 0) {
        pmax[(size_t)rowg * PSTRIDE + chunk] = mv;
        psum[(size_t)rowg * PSTRIDE + chunk] = se;
      }
      int cw = target[rowg] - colbase;
      if (cw >= 0 && cw < 64 && lr == (cw & 31)) {
        tlog[rowg] = (cw < 32) ? v0 : v1;
      }
    }
  }
}

// ---------------- combine per-chunk stats -> nll per row ----------------
__global__ void k_reduce_nll(const float* __restrict__ pmax,
                             const float* __restrict__ psum,
                             const float* __restrict__ tlog,
                             float* __restrict__ nll) {
  int row = blockIdx.x;
  int lane = threadIdx.x; // 64
  float M = -1e30f;
  for (int ch = lane; ch < NCHUNK; ch += 64) M = fmaxf(M, pmax[(size_t)row * PSTRIDE + ch]);
#pragma unroll
  for (int s = 1; s < 64; s <<= 1) M = fmaxf(M, __shfl_xor(M, s));
  float L = 0.f;
  for (int ch = lane; ch < NCHUNK; ch += 64)
    L += __expf(pmax[(size_t)row * PSTRIDE + ch] - M) * psum[(size_t)row * PSTRIDE + ch];
#pragma unroll
  for (int s = 1; s < 64; s <<= 1) L += __shfl_xor(L, s);
  if (lane == 0) nll[row] = -(tlog[row] - M - logf(L));
}

// ---------------- masked per-step mean -> scalar loss ----------------
__global__ void k_loss(const int* __restrict__ target,
                       const float* __restrict__ nll,
                       float* __restrict__ out) {
  __shared__ float red[SS];
  int s = threadIdx.x; // 512
  float sl = 0.f, cnt = 0.f;
#pragma unroll
  for (int b = 0; b < NB; ++b) {
    int idx = b * SS + s;
    if (target[idx] != 0) { sl += nll[idx]; cnt += 1.f; }
  }
  red[s] = sl / fmaxf(cnt, 1.f);
  __syncthreads();
  for (int st = 256; st > 0; st >>= 1) {
    if (s < st) red[s] += red[s + st];
    __syncthreads();
  }
  if (s == 0) out[0] = red[0] / (float)SS;
}

// ---------------- launch ----------------
extern "C" void kernel_launch(void* const* d_in, const int* in_sizes, int n_in,
                              void* d_out, int out_size, void* d_ws, size_t ws_size,
                              hipStream_t stream) {
  (void)in_sizes; (void)n_in; (void)out_size; (void)ws_size;
  const int*   text   = (const int*)d_in[0];
  const int*   target = (const int*)d_in[1];
  const float* embed  = (const float*)d_in[2];
  const float* W1     = (const float*)d_in[3];
  const float* b1     = (const float*)d_in[4];
  const float* W2     = (const float*)d_in[5];
  const float* b2     = (const float*)d_in[6];
  const float* Wo     = (const float*)d_in[7];
  const float* bo     = (const float*)d_in[8];
  float* out = (float*)d_out;
  char* ws = (char*)d_ws;

  const size_t SZ_E = (size_t)MTOK * KDIM * 2;          // 16.78 MB (bf16)
  unsigned short* E   = (unsigned short*)(ws);
  unsigned short* H1  = (unsigned short*)(ws + SZ_E);
  uint8_t*        H2Q = (uint8_t*)(ws + 2 * SZ_E);      // fp8, 8.39 MB
  char* p = ws + 2 * SZ_E + (size_t)MTOK * KDIM;
  unsigned short* W1t = (unsigned short*)p;  p += (size_t)HID * HID * 2;
  unsigned short* W2t = (unsigned short*)p;  p += (size_t)HID * HID * 2;
  uint8_t*        WoQ = (uint8_t*)p;         p += (size_t)VOCAB * HID;   // fp8, 32.77 MB
  float* tlog = (float*)p;                   p += (size_t)MTOK * 4;
  float* nll  = (float*)p;
  float* pmax = (float*)E;   // E dead after GEMM1
  float* psum = (float*)H1;  // H1 dead after GEMM2

  k_transpose_bf16<<<dim3(HID / 32, HID / 32), 256, 0, stream>>>(W1, W1t, HID, HID);
  k_transpose_bf16<<<dim3(HID / 32, HID / 32), 256, 0, stream>>>(W2, W2t, HID, HID);
  k_transpose_fp8 <<<dim3(VOCAB / 32, HID / 32), 256, 0, stream>>>(Wo, WoQ, HID, VOCAB);
  k_gather_e<<<MTOK, 256, 0, stream>>>(text, embed, E);

  k_gemm_ffn<0><<<dim3(HID / 128, MTOK / 128), 256, 0, stream>>>(E, W1t, b1, (void*)H1, HID);
  k_gemm_ffn<1><<<dim3(HID / 128, MTOK / 128), 256, 0, stream>>>(H1, W2t, b2, (void*)H2Q, HID);

  k_gemm_vocab_mx<<<dim3((MTOK / 256) * (VOCAB / 128)), 256, 0, stream>>>(
      H2Q, WoQ, bo, pmax, psum, tlog, target);

  k_reduce_nll<<<MTOK, 64, 0, stream>>>(pmax, psum, tlog, nll);
  k_loss<<<1, SS, 0, stream>>>(target, nll, out);
}

// Round 6
// 1490.247 us; speedup vs baseline: 1.6165x; 1.2903x over previous
//
#include <hip/hip_runtime.h>
#include <cstdint>
#include <cstddef>

// ---------------- problem constants ----------------
#define VOCAB 32000
#define EMB   256
#define HID   1024
#define NB    16      // batch
#define SS    512     // seq
#define MTOK  (NB*SS) // 8192 tokens
#define KDIM  1024    // NM1*EMB = HID
#define NCHUNK 500    // 32000 / 64 cols per wave-chunk
#define PSTRIDE 512   // padded chunk stride

typedef __bf16 bf16_t;
typedef bf16_t bf16x8 __attribute__((ext_vector_type(8)));
typedef float  f32x4  __attribute__((ext_vector_type(4)));
typedef float  f32x16 __attribute__((ext_vector_type(16)));
typedef int    i32x4  __attribute__((ext_vector_type(4)));
typedef int    i32x8  __attribute__((ext_vector_type(8)));

__device__ __forceinline__ unsigned short f32_to_bf16(float f) {
  union { float f; unsigned int u; } v; v.f = f;
  unsigned int u = v.u;
  unsigned int r = (u + 0x7FFFu + ((u >> 16) & 1u)) >> 16; // RNE
  return (unsigned short)r;
}

// f32 -> OCP e4m3fn, RNE, software (input assumed |x| <= 448)
__device__ __forceinline__ uint8_t f32_to_e4m3(float x) {
  union { float f; uint32_t u; } v; v.f = x;
  uint32_t s = (v.u >> 24) & 0x80u;
  int e = (int)((v.u >> 23) & 0xffu) - 127;
  uint32_t m = v.u & 0x7fffffu;
  if (e < -9) return (uint8_t)s;                  // -> 0
  if (e >= -6) {                                  // normal range
    uint32_t keep = m >> 20;
    uint32_t rest = m & 0xfffffu;
    keep += (rest > 0x80000u) || (rest == 0x80000u && (keep & 1u));
    if (keep == 8u) { keep = 0u; e += 1; }
    int code = ((e + 7) << 3) | (int)keep;
    if (code >= 0x7f) code = 0x7e;                // clamp to 448 (avoid NaN)
    return (uint8_t)(s | (uint32_t)code);
  }
  // subnormal
  uint32_t full = 0x800000u | m;
  int shift = 20 + (-6 - e);                      // 21..23
  uint32_t keep = full >> shift;
  uint32_t rest = full & ((1u << shift) - 1u);
  uint32_t half = 1u << (shift - 1);
  keep += (rest > half) || (rest == half && (keep & 1u));
  if (keep >= 8u) return (uint8_t)(s | 0x08u);
  return (uint8_t)(s | keep);
}

__device__ __forceinline__ void gload_lds16(const void* gsrc, void* ldst) {
  __builtin_amdgcn_global_load_lds(
      (__attribute__((address_space(1))) void*)gsrc,
      (__attribute__((address_space(3))) void*)ldst,
      16, 0, 0);
}

// ---------------- transpose + convert: in[R][C] f32 -> out[C][R] ----------------
__global__ void k_transpose_bf16(const float* __restrict__ in,
                                 unsigned short* __restrict__ out,
                                 int R, int C) {
  __shared__ float tile[32][33];
  int bc = blockIdx.x * 32, br = blockIdx.y * 32;
  int tx = threadIdx.x & 31, ty = threadIdx.x >> 5;
#pragma unroll
  for (int i = 0; i < 32; i += 8)
    tile[ty + i][tx] = in[(size_t)(br + ty + i) * C + (bc + tx)];
  __syncthreads();
#pragma unroll
  for (int i = 0; i < 32; i += 8)
    out[(size_t)(bc + ty + i) * R + (br + tx)] = f32_to_bf16(tile[tx][ty + i]);
}

__global__ void k_transpose_fp8(const float* __restrict__ in,
                                uint8_t* __restrict__ out,
                                int R, int C) {
  __shared__ float tile[32][33];
  int bc = blockIdx.x * 32, br = blockIdx.y * 32;
  int tx = threadIdx.x & 31, ty = threadIdx.x >> 5;
#pragma unroll
  for (int i = 0; i < 32; i += 8)
    tile[ty + i][tx] = in[(size_t)(br + ty + i) * C + (bc + tx)];
  __syncthreads();
#pragma unroll
  for (int i = 0; i < 32; i += 8)
    out[(size_t)(bc + ty + i) * R + (br + tx)] = f32_to_e4m3(tile[tx][ty + i] * 16.0f);
}

// ---------------- embedding gather ----------------
__global__ void k_gather_e(const int* __restrict__ text,
                           const float* __restrict__ embed,
                           unsigned short* __restrict__ E) {
  int t = blockIdx.x;
  int b = t >> 9, s = t & 511;
  int d = threadIdx.x; // 0..255
#pragma unroll
  for (int j = 0; j < 4; ++j) {
    int sidx = s + j - 4;
    int tok = (sidx >= 0) ? text[b * SS + sidx] : 0;
    float val = (tok != 0) ? embed[(size_t)tok * EMB + d] : 0.0f;
    E[(size_t)t * KDIM + j * EMB + d] = f32_to_bf16(val);
  }
}

// ---------------- FFN GEMM (128x128 tile, relu+bias; OUTQ=1 -> fp8 x16) ----------------
template<int OUTQ>
__global__ __launch_bounds__(256)
void k_gemm_ffn(const unsigned short* __restrict__ A,
                const unsigned short* __restrict__ Bt,
                const float* __restrict__ bias,
                void* __restrict__ Hout, int N) {
  __shared__ unsigned short As[128 * 32];
  __shared__ unsigned short Bs[128 * 32];
  const int tid  = threadIdx.x;
  const int bn   = blockIdx.x, bm = blockIdx.y;
  const int lane = tid & 63, wid = tid >> 6;
  const int wm = wid >> 1, wn = wid & 1;
  const int g = lane >> 4, c = lane & 15;

  f32x4 acc[4][4];
#pragma unroll
  for (int m = 0; m < 4; ++m)
#pragma unroll
    for (int n = 0; n < 4; ++n) { f32x4 z = {0.f, 0.f, 0.f, 0.f}; acc[m][n] = z; }

  const int arow = tid >> 2;
  const int slotb = ((tid & 3) ^ ((tid >> 3) & 3)) * 16;
  const char* gA0 = (const char*)A + ((size_t)(bm * 128 + arow) * KDIM) * 2 + slotb;
  const char* gA1 = gA0 + (size_t)64 * KDIM * 2;
  const char* gB0 = (const char*)Bt + ((size_t)(bn * 128 + arow) * KDIM) * 2 + slotb;
  const char* gB1 = gB0 + (size_t)64 * KDIM * 2;
  char* lA = (char*)As + tid * 16;
  char* lB = (char*)Bs + tid * 16;

  const int rs = (g ^ ((c >> 1) & 3)) * 8;

  for (int kt = 0; kt < KDIM / 32; ++kt) {
    const int kb = kt * 64;
    gload_lds16(gA0 + kb, lA);
    gload_lds16(gA1 + kb, lA + 4096);
    gload_lds16(gB0 + kb, lB);
    gload_lds16(gB1 + kb, lB + 4096);
    __syncthreads();

    bf16x8 af[4], bf[4];
#pragma unroll
    for (int m = 0; m < 4; ++m)
      af[m] = *(const bf16x8*)&As[(wm * 64 + m * 16 + c) * 32 + rs];
#pragma unroll
    for (int n = 0; n < 4; ++n)
      bf[n] = *(const bf16x8*)&Bs[(wn * 64 + n * 16 + c) * 32 + rs];
#pragma unroll
    for (int m = 0; m < 4; ++m)
#pragma unroll
      for (int n = 0; n < 4; ++n)
        acc[m][n] = __builtin_amdgcn_mfma_f32_16x16x32_bf16(af[m], bf[n], acc[m][n], 0, 0, 0);
    __syncthreads();
  }

#pragma unroll
  for (int n = 0; n < 4; ++n) {
    int colg = bn * 128 + wn * 64 + n * 16 + c;
    float bv = bias[colg];
#pragma unroll
    for (int m = 0; m < 4; ++m)
#pragma unroll
      for (int j = 0; j < 4; ++j) {
        int rowg = bm * 128 + wm * 64 + m * 16 + g * 4 + j;
        float v = acc[m][n][j] + bv;
        v = v > 0.f ? v : 0.f;
        if constexpr (OUTQ == 0)
          ((unsigned short*)Hout)[(size_t)rowg * N + colg] = f32_to_bf16(v);
        else
          ((uint8_t*)Hout)[(size_t)rowg * N + colg] = f32_to_e4m3(v * 16.0f);
      }
  }
}

// ---------------- vocab GEMM: MX-fp8, 256x128 tile, BK=64, 4 waves, dbuf 2-phase ------
// A/B pre-scaled by 2^4; MFMA scale operands 2^-4 (e8m0 byte 123).
// Register-pressure discipline (R5 spilled 1.76 GB):
//  - __launch_bounds__(256,1): permit up to 512 unified VGPRs, never spill.
//  - static-buffer two-body K loop (#pragma unroll 1): no runtime dbuf index.
//  - minimal operand liveness: b0/b1 preloaded (16 regs); per-m a-operand (8 regs)
//    loaded immediately before its 2 MFMAs.
__global__ __launch_bounds__(256, 1)
void k_gemm_vocab_mx(const uint8_t* __restrict__ Aq,   // [MTOK][KDIM] fp8 (x16)
                     const uint8_t* __restrict__ Bq,   // [VOCAB][KDIM] fp8 (x16)
                     const float* __restrict__ bias,
                     float* __restrict__ pmax, float* __restrict__ psum,
                     float* __restrict__ tlog, const int* __restrict__ target) {
  __shared__ uint8_t As[2][256 * 64];  // 32 KB
  __shared__ uint8_t Bs[2][128 * 64];  // 16 KB
  const int tid  = threadIdx.x;
  const int lane = tid & 63, wid = tid >> 6;   // 4 waves
  const int wm = wid >> 1, wn = wid & 1;       // 2(M) x 2(N); per-wave out 128x64
  const int lr = lane & 31, kb = lane >> 5;
  const int kb2 = kb << 1;

  // XCD-chunked swizzle; grid = 8000 = 32(bm) x 250(bn)
  const int o   = blockIdx.x;
  const int xcd = o & 7, idx = o >> 3;         // idx 0..999
  const int bm  = xcd * 4 + (idx & 3);         // 0..31
  const int bn  = idx >> 2;                    // 0..249

  f32x16 acc[4][2];
#pragma unroll
  for (int m = 0; m < 4; ++m)
#pragma unroll
    for (int n = 0; n < 2; ++n)
#pragma unroll
      for (int e = 0; e < 16; ++e) acc[m][n][e] = 0.f;

  // staging: thread t -> row (t>>2)+64h, LDS quad t&3; source quad (t&3)^((row>>1)&3)
  const int srow = tid >> 2, sq = tid & 3;
  const int gq = sq ^ ((srow >> 1) & 3);       // invariant under row+=64
  const uint8_t* gA = Aq + (size_t)(bm * 256 + srow) * KDIM + gq * 16;
  const uint8_t* gB = Bq + (size_t)(bn * 128 + srow) * KDIM + gq * 16;

#define STAGE(kt, d) do {                                                  \
    const size_t ko_ = (size_t)(kt) * 64;                                  \
    uint8_t* la_ = &As[d][0] + tid * 16;                                   \
    uint8_t* lb_ = &Bs[d][0] + tid * 16;                                   \
    _Pragma("unroll") for (int h = 0; h < 4; ++h)                          \
      gload_lds16(gA + ko_ + (size_t)h * 64 * KDIM, la_ + h * 4096);       \
    _Pragma("unroll") for (int h = 0; h < 2; ++h)                          \
      gload_lds16(gB + ko_ + (size_t)h * 64 * KDIM, lb_ + h * 4096);       \
  } while (0)

  const int swz = (lr >> 1) & 3;

  // BODY: consume buffer B (K-tile T); optionally prefetch tile T+1 into B^1.
#define BODY(B, T, DOSTAGE) do {                                           \
    if (DOSTAGE) STAGE((T) + 1, (B) ^ 1);                                  \
    i32x8 b0, b1;                                                          \
    {                                                                      \
      const uint8_t* pb = &Bs[B][0] + (wn * 64 + lr) * 64;                 \
      i32x4 lo = *(const i32x4*)(pb + ((kb2 | 0) ^ swz) * 16);             \
      i32x4 hi = *(const i32x4*)(pb + ((kb2 | 1) ^ swz) * 16);             \
      b0 = __builtin_shufflevector(lo, hi, 0, 1, 2, 3, 4, 5, 6, 7);        \
      pb += 32 * 64;                                                       \
      lo = *(const i32x4*)(pb + ((kb2 | 0) ^ swz) * 16);                   \
      hi = *(const i32x4*)(pb + ((kb2 | 1) ^ swz) * 16);                   \
      b1 = __builtin_shufflevector(lo, hi, 0, 1, 2, 3, 4, 5, 6, 7);        \
    }                                                                      \
    _Pragma("unroll") for (int m = 0; m < 4; ++m) {                        \
      const uint8_t* pa = &As[B][0] + (wm * 128 + m * 32 + lr) * 64;       \
      i32x4 lo = *(const i32x4*)(pa + ((kb2 | 0) ^ swz) * 16);             \
      i32x4 hi = *(const i32x4*)(pa + ((kb2 | 1) ^ swz) * 16);             \
      i32x8 am = __builtin_shufflevector(lo, hi, 0, 1, 2, 3, 4, 5, 6, 7);  \
      acc[m][0] = __builtin_amdgcn_mfma_scale_f32_32x32x64_f8f6f4(         \
          am, b0, acc[m][0], 0, 0, 0, 123, 0, 123);                        \
      acc[m][1] = __builtin_amdgcn_mfma_scale_f32_32x32x64_f8f6f4(         \
          am, b1, acc[m][1], 0, 0, 0, 123, 0, 123);                        \
    }                                                                      \
    __syncthreads();                                                       \
  } while (0)

  STAGE(0, 0);
  __syncthreads();  // tile 0 resident

#pragma unroll 1
  for (int ktp = 0; ktp < 8; ++ktp) {
    BODY(0, 2 * ktp,     true);        // stages 2*ktp+1 -> buf1
    BODY(1, 2 * ktp + 1, (ktp < 7));   // stages 2*ktp+2 -> buf0
  }
#undef STAGE
#undef BODY

  // ---- epilogue: fused softmax stats per 64-col wave chunk ----
  // C/D 32x32 layout: col = lane&31, row = (reg&3) + 8*(reg>>2) + 4*(lane>>5)
  const int chunk = bn * 2 + wn;
  const int colbase = bn * 128 + wn * 64;
  float bov0 = bias[colbase + lr];
  float bov1 = bias[colbase + 32 + lr];
#pragma unroll
  for (int m = 0; m < 4; ++m) {
#pragma unroll
    for (int reg = 0; reg < 16; ++reg) {
      int rowg = bm * 256 + wm * 128 + m * 32 + (reg & 3) + 8 * (reg >> 2) + 4 * kb;
      float v0 = acc[m][0][reg] + bov0;
      float v1 = acc[m][1][reg] + bov1;
      float mv = fmaxf(v0, v1);
#pragma unroll
      for (int sft = 1; sft < 32; sft <<= 1) mv = fmaxf(mv, __shfl_xor(mv, sft));
      float se = __expf(v0 - mv) + __expf(v1 - mv);
#pragma unroll
      for (int sft = 1; sft < 32; sft <<= 1) se += __shfl_xor(se, sft);
      if (lr == 0) {
        pmax[(size_t)rowg * PSTRIDE + chunk] = mv;
        psum[(size_t)rowg * PSTRIDE + chunk] = se;
      }
      int cw = target[rowg] - colbase;
      if (cw >= 0 && cw < 64 && lr == (cw & 31)) {
        tlog[rowg] = (cw < 32) ? v0 : v1;
      }
    }
  }
}

// ---------------- combine per-chunk stats -> nll per row ----------------
__global__ void k_reduce_nll(const float* __restrict__ pmax,
                             const float* __restrict__ psum,
                             const float* __restrict__ tlog,
                             float* __restrict__ nll) {
  int row = blockIdx.x;
  int lane = threadIdx.x; // 64
  float M = -1e30f;
  for (int ch = lane; ch < NCHUNK; ch += 64) M = fmaxf(M, pmax[(size_t)row * PSTRIDE + ch]);
#pragma unroll
  for (int s = 1; s < 64; s <<= 1) M = fmaxf(M, __shfl_xor(M, s));
  float L = 0.f;
  for (int ch = lane; ch < NCHUNK; ch += 64)
    L += __expf(pmax[(size_t)row * PSTRIDE + ch] - M) * psum[(size_t)row * PSTRIDE + ch];
#pragma unroll
  for (int s = 1; s < 64; s <<= 1) L += __shfl_xor(L, s);
  if (lane == 0) nll[row] = -(tlog[row] - M - logf(L));
}

// ---------------- masked per-step mean -> scalar loss ----------------
__global__ void k_loss(const int* __restrict__ target,
                       const float* __restrict__ nll,
                       float* __restrict__ out) {
  __shared__ float red[SS];
  int s = threadIdx.x; // 512
  float sl = 0.f, cnt = 0.f;
#pragma unroll
  for (int b = 0; b < NB; ++b) {
    int idx = b * SS + s;
    if (target[idx] != 0) { sl += nll[idx]; cnt += 1.f; }
  }
  red[s] = sl / fmaxf(cnt, 1.f);
  __syncthreads();
  for (int st = 256; st > 0; st >>= 1) {
    if (s < st) red[s] += red[s + st];
    __syncthreads();
  }
  if (s == 0) out[0] = red[0] / (float)SS;
}

// ---------------- launch ----------------
extern "C" void kernel_launch(void* const* d_in, const int* in_sizes, int n_in,
                              void* d_out, int out_size, void* d_ws, size_t ws_size,
                              hipStream_t stream) {
  (void)in_sizes; (void)n_in; (void)out_size; (void)ws_size;
  const int*   text   = (const int*)d_in[0];
  const int*   target = (const int*)d_in[1];
  const float* embed  = (const float*)d_in[2];
  const float* W1     = (const float*)d_in[3];
  const float* b1     = (const float*)d_in[4];
  const float* W2     = (const float*)d_in[5];
  const float* b2     = (const float*)d_in[6];
  const float* Wo     = (const float*)d_in[7];
  const float* bo     = (const float*)d_in[8];
  float* out = (float*)d_out;
  char* ws = (char*)d_ws;

  const size_t SZ_E = (size_t)MTOK * KDIM * 2;          // 16.78 MB (bf16)
  unsigned short* E   = (unsigned short*)(ws);
  unsigned short* H1  = (unsigned short*)(ws + SZ_E);
  uint8_t*        H2Q = (uint8_t*)(ws + 2 * SZ_E);      // fp8, 8.39 MB
  char* p = ws + 2 * SZ_E + (size_t)MTOK * KDIM;
  unsigned short* W1t = (unsigned short*)p;  p += (size_t)HID * HID * 2;
  unsigned short* W2t = (unsigned short*)p;  p += (size_t)HID * HID * 2;
  uint8_t*        WoQ = (uint8_t*)p;         p += (size_t)VOCAB * HID;   // fp8, 32.77 MB
  float* tlog = (float*)p;                   p += (size_t)MTOK * 4;
  float* nll  = (float*)p;
  float* pmax = (float*)E;   // E dead after GEMM1
  float* psum = (float*)H1;  // H1 dead after GEMM2

  k_transpose_bf16<<<dim3(HID / 32, HID / 32), 256, 0, stream>>>(W1, W1t, HID, HID);
  k_transpose_bf16<<<dim3(HID / 32, HID / 32), 256, 0, stream>>>(W2, W2t, HID, HID);
  k_transpose_fp8 <<<dim3(VOCAB / 32, HID / 32), 256, 0, stream>>>(Wo, WoQ, HID, VOCAB);
  k_gather_e<<<MTOK, 256, 0, stream>>>(text, embed, E);

  k_gemm_ffn<0><<<dim3(HID / 128, MTOK / 128), 256, 0, stream>>>(E, W1t, b1, (void*)H1, HID);
  k_gemm_ffn<1><<<dim3(HID / 128, MTOK / 128), 256, 0, stream>>>(H1, W2t, b2, (void*)H2Q, HID);

  k_gemm_vocab_mx<<<dim3((MTOK / 256) * (VOCAB / 128)), 256, 0, stream>>>(
      H2Q, WoQ, bo, pmax, psum, tlog, target);

  k_reduce_nll<<<MTOK, 64, 0, stream>>>(pmax, psum, tlog, nll);
  k_loss<<<1, SS, 0, stream>>>(target, nll, out);
}

// Round 7
// 636.436 us; speedup vs baseline: 3.7851x; 2.3416x over previous
//
#include <hip/hip_runtime.h>
#include <cstdint>
#include <cstddef>

// ---------------- problem constants ----------------
#define VOCAB 32000
#define EMB   256
#define HID   1024
#define NB    16      // batch
#define SS    512     // seq
#define MTOK  (NB*SS) // 8192 tokens
#define KDIM  1024    // NM1*EMB = HID
#define NCHUNK 500    // 32000 / 64 cols per wave-chunk
#define PSTRIDE 512   // padded chunk stride

typedef __bf16 bf16_t;
typedef bf16_t bf16x8 __attribute__((ext_vector_type(8)));
typedef float  f32x4  __attribute__((ext_vector_type(4)));
typedef float  f32x16 __attribute__((ext_vector_type(16)));
typedef int    i32x4  __attribute__((ext_vector_type(4)));
typedef int    i32x8  __attribute__((ext_vector_type(8)));

__device__ __forceinline__ unsigned short f32_to_bf16(float f) {
  union { float f; unsigned int u; } v; v.f = f;
  unsigned int u = v.u;
  unsigned int r = (u + 0x7FFFu + ((u >> 16) & 1u)) >> 16; // RNE
  return (unsigned short)r;
}

// f32 -> OCP e4m3fn, RNE, software (input assumed |x| <= 448)
__device__ __forceinline__ uint8_t f32_to_e4m3(float x) {
  union { float f; uint32_t u; } v; v.f = x;
  uint32_t s = (v.u >> 24) & 0x80u;
  int e = (int)((v.u >> 23) & 0xffu) - 127;
  uint32_t m = v.u & 0x7fffffu;
  if (e < -9) return (uint8_t)s;                  // -> 0
  if (e >= -6) {                                  // normal range
    uint32_t keep = m >> 20;
    uint32_t rest = m & 0xfffffu;
    keep += (rest > 0x80000u) || (rest == 0x80000u && (keep & 1u));
    if (keep == 8u) { keep = 0u; e += 1; }
    int code = ((e + 7) << 3) | (int)keep;
    if (code >= 0x7f) code = 0x7e;                // clamp to 448 (avoid NaN)
    return (uint8_t)(s | (uint32_t)code);
  }
  // subnormal
  uint32_t full = 0x800000u | m;
  int shift = 20 + (-6 - e);                      // 21..23
  uint32_t keep = full >> shift;
  uint32_t rest = full & ((1u << shift) - 1u);
  uint32_t half = 1u << (shift - 1);
  keep += (rest > half) || (rest == half && (keep & 1u));
  if (keep >= 8u) return (uint8_t)(s | 0x08u);
  return (uint8_t)(s | keep);
}

__device__ __forceinline__ void gload_lds16(const void* gsrc, void* ldst) {
  __builtin_amdgcn_global_load_lds(
      (__attribute__((address_space(1))) void*)gsrc,
      (__attribute__((address_space(3))) void*)ldst,
      16, 0, 0);
}

// ---------------- transpose + convert: in[R][C] f32 -> out[C][R] ----------------
__global__ void k_transpose_bf16(const float* __restrict__ in,
                                 unsigned short* __restrict__ out,
                                 int R, int C) {
  __shared__ float tile[32][33];
  int bc = blockIdx.x * 32, br = blockIdx.y * 32;
  int tx = threadIdx.x & 31, ty = threadIdx.x >> 5;
#pragma unroll
  for (int i = 0; i < 32; i += 8)
    tile[ty + i][tx] = in[(size_t)(br + ty + i) * C + (bc + tx)];
  __syncthreads();
#pragma unroll
  for (int i = 0; i < 32; i += 8)
    out[(size_t)(bc + ty + i) * R + (br + tx)] = f32_to_bf16(tile[tx][ty + i]);
}

__global__ void k_transpose_fp8(const float* __restrict__ in,
                                uint8_t* __restrict__ out,
                                int R, int C) {
  __shared__ float tile[32][33];
  int bc = blockIdx.x * 32, br = blockIdx.y * 32;
  int tx = threadIdx.x & 31, ty = threadIdx.x >> 5;
#pragma unroll
  for (int i = 0; i < 32; i += 8)
    tile[ty + i][tx] = in[(size_t)(br + ty + i) * C + (bc + tx)];
  __syncthreads();
#pragma unroll
  for (int i = 0; i < 32; i += 8)
    out[(size_t)(bc + ty + i) * R + (br + tx)] = f32_to_e4m3(tile[tx][ty + i] * 16.0f);
}

// ---------------- embedding gather ----------------
__global__ void k_gather_e(const int* __restrict__ text,
                           const float* __restrict__ embed,
                           unsigned short* __restrict__ E) {
  int t = blockIdx.x;
  int b = t >> 9, s = t & 511;
  int d = threadIdx.x; // 0..255
#pragma unroll
  for (int j = 0; j < 4; ++j) {
    int sidx = s + j - 4;
    int tok = (sidx >= 0) ? text[b * SS + sidx] : 0;
    float val = (tok != 0) ? embed[(size_t)tok * EMB + d] : 0.0f;
    E[(size_t)t * KDIM + j * EMB + d] = f32_to_bf16(val);
  }
}

// ---------------- FFN GEMM (128x128 tile, relu+bias; OUTQ=1 -> fp8 x16) ----------------
template<int OUTQ>
__global__ __launch_bounds__(256)
void k_gemm_ffn(const unsigned short* __restrict__ A,
                const unsigned short* __restrict__ Bt,
                const float* __restrict__ bias,
                void* __restrict__ Hout, int N) {
  __shared__ unsigned short As[128 * 32];
  __shared__ unsigned short Bs[128 * 32];
  const int tid  = threadIdx.x;
  const int bn   = blockIdx.x, bm = blockIdx.y;
  const int lane = tid & 63, wid = tid >> 6;
  const int wm = wid >> 1, wn = wid & 1;
  const int g = lane >> 4, c = lane & 15;

  f32x4 acc[4][4];
#pragma unroll
  for (int m = 0; m < 4; ++m)
#pragma unroll
    for (int n = 0; n < 4; ++n) { f32x4 z = {0.f, 0.f, 0.f, 0.f}; acc[m][n] = z; }

  const int arow = tid >> 2;
  const int slotb = ((tid & 3) ^ ((tid >> 3) & 3)) * 16;
  const char* gA0 = (const char*)A + ((size_t)(bm * 128 + arow) * KDIM) * 2 + slotb;
  const char* gA1 = gA0 + (size_t)64 * KDIM * 2;
  const char* gB0 = (const char*)Bt + ((size_t)(bn * 128 + arow) * KDIM) * 2 + slotb;
  const char* gB1 = gB0 + (size_t)64 * KDIM * 2;
  char* lA = (char*)As + tid * 16;
  char* lB = (char*)Bs + tid * 16;

  const int rs = (g ^ ((c >> 1) & 3)) * 8;

  for (int kt = 0; kt < KDIM / 32; ++kt) {
    const int kb = kt * 64;
    gload_lds16(gA0 + kb, lA);
    gload_lds16(gA1 + kb, lA + 4096);
    gload_lds16(gB0 + kb, lB);
    gload_lds16(gB1 + kb, lB + 4096);
    __syncthreads();

    bf16x8 af[4], bf[4];
#pragma unroll
    for (int m = 0; m < 4; ++m)
      af[m] = *(const bf16x8*)&As[(wm * 64 + m * 16 + c) * 32 + rs];
#pragma unroll
    for (int n = 0; n < 4; ++n)
      bf[n] = *(const bf16x8*)&Bs[(wn * 64 + n * 16 + c) * 32 + rs];
#pragma unroll
    for (int m = 0; m < 4; ++m)
#pragma unroll
      for (int n = 0; n < 4; ++n)
        acc[m][n] = __builtin_amdgcn_mfma_f32_16x16x32_bf16(af[m], bf[n], acc[m][n], 0, 0, 0);
    __syncthreads();
  }

#pragma unroll
  for (int n = 0; n < 4; ++n) {
    int colg = bn * 128 + wn * 64 + n * 16 + c;
    float bv = bias[colg];
#pragma unroll
    for (int m = 0; m < 4; ++m)
#pragma unroll
      for (int j = 0; j < 4; ++j) {
        int rowg = bm * 128 + wm * 64 + m * 16 + g * 4 + j;
        float v = acc[m][n][j] + bv;
        v = v > 0.f ? v : 0.f;
        if constexpr (OUTQ == 0)
          ((unsigned short*)Hout)[(size_t)rowg * N + colg] = f32_to_bf16(v);
        else
          ((uint8_t*)Hout)[(size_t)rowg * N + colg] = f32_to_e4m3(v * 16.0f);
      }
  }
}

// ---------------- vocab GEMM: MX-fp8, 128x128 tile, BK=64, 4 waves, dbuf 2-phase ------
// A/B pre-scaled by 2^4; MFMA scale operands 2^-4 (e8m0 byte 123).
// Occupancy discipline (R6 lesson: VGPR_Count excludes AGPRs; 148 arch + 128 acc = 276
// unified -> 1 wave/SIMD, 90% stall). Here acc = 2x2xf32x16 = 64 regs -> total ~160:
// 2-3 INDEPENDENT blocks/CU, so one block's vmcnt/barrier stall hides under another's
// MFMA. __launch_bounds__(256,2) caps unified alloc at 256 (no spill at ~160 need).
__global__ __launch_bounds__(256, 2)
void k_gemm_vocab_mx(const uint8_t* __restrict__ Aq,   // [MTOK][KDIM] fp8 (x16)
                     const uint8_t* __restrict__ Bq,   // [VOCAB][KDIM] fp8 (x16)
                     const float* __restrict__ bias,
                     float* __restrict__ pmax, float* __restrict__ psum,
                     float* __restrict__ tlog, const int* __restrict__ target) {
  __shared__ uint8_t As[2][128 * 64];  // 16 KB
  __shared__ uint8_t Bs[2][128 * 64];  // 16 KB
  const int tid  = threadIdx.x;
  const int lane = tid & 63, wid = tid >> 6;   // 4 waves
  const int wm = wid >> 1, wn = wid & 1;       // 2(M) x 2(N); per-wave out 64x64
  const int lr = lane & 31, kb = lane >> 5;
  const int kb2 = kb << 1;

  // bijective XCD-chunked swizzle; grid = 16000 = 64(bm) x 250(bn)
  const int o   = blockIdx.x;
  const int xcd = o & 7, idx = o >> 3;         // idx 0..1999
  const int bm  = xcd * 8 + (idx & 7);         // 0..63
  const int bn  = idx >> 3;                    // 0..249

  f32x16 acc[2][2];
#pragma unroll
  for (int m = 0; m < 2; ++m)
#pragma unroll
    for (int n = 0; n < 2; ++n)
#pragma unroll
      for (int e = 0; e < 16; ++e) acc[m][n][e] = 0.f;

  // staging: thread t -> row (t>>2)+64h, LDS quad t&3; source quad (t&3)^((row>>1)&3)
  // (row>>1)&3 invariant under row += 64, so one gq serves both h issues.
  const int srow = tid >> 2, sq = tid & 3;
  const int gq = sq ^ ((srow >> 1) & 3);
  const size_t voffA = (size_t)srow * KDIM + gq * 16;  // per-thread offset (uniform base below)
  const uint8_t* Abase = Aq + (size_t)bm * 128 * KDIM;
  const uint8_t* Bbase = Bq + (size_t)bn * 128 * KDIM;

#define STAGE(kt, d) do {                                                  \
    const size_t ko_ = (size_t)(kt) * 64;                                  \
    uint8_t* la_ = &As[d][0] + tid * 16;                                   \
    uint8_t* lb_ = &Bs[d][0] + tid * 16;                                   \
    gload_lds16(Abase + voffA + ko_,         la_);                         \
    gload_lds16(Abase + voffA + ko_ + 65536, la_ + 4096);                  \
    gload_lds16(Bbase + voffA + ko_,         lb_);                         \
    gload_lds16(Bbase + voffA + ko_ + 65536, lb_ + 4096);                  \
  } while (0)

  const int swz = (lr >> 1) & 3;

  // BODY: consume buffer B (K-tile T); optionally prefetch tile T+1 into B^1.
#define BODY(B, T, DOSTAGE) do {                                           \
    if (DOSTAGE) STAGE((T) + 1, (B) ^ 1);                                  \
    i32x8 b0, b1;                                                          \
    {                                                                      \
      const uint8_t* pb = &Bs[B][0] + (wn * 64 + lr) * 64;                 \
      i32x4 lo = *(const i32x4*)(pb + ((kb2 | 0) ^ swz) * 16);             \
      i32x4 hi = *(const i32x4*)(pb + ((kb2 | 1) ^ swz) * 16);             \
      b0 = __builtin_shufflevector(lo, hi, 0, 1, 2, 3, 4, 5, 6, 7);        \
      pb += 32 * 64;                                                       \
      lo = *(const i32x4*)(pb + ((kb2 | 0) ^ swz) * 16);                   \
      hi = *(const i32x4*)(pb + ((kb2 | 1) ^ swz) * 16);                   \
      b1 = __builtin_shufflevector(lo, hi, 0, 1, 2, 3, 4, 5, 6, 7);        \
    }                                                                      \
    _Pragma("unroll") for (int m = 0; m < 2; ++m) {                        \
      const uint8_t* pa = &As[B][0] + (wm * 64 + m * 32 + lr) * 64;        \
      i32x4 lo = *(const i32x4*)(pa + ((kb2 | 0) ^ swz) * 16);             \
      i32x4 hi = *(const i32x4*)(pa + ((kb2 | 1) ^ swz) * 16);             \
      i32x8 am = __builtin_shufflevector(lo, hi, 0, 1, 2, 3, 4, 5, 6, 7);  \
      acc[m][0] = __builtin_amdgcn_mfma_scale_f32_32x32x64_f8f6f4(         \
          am, b0, acc[m][0], 0, 0, 0, 123, 0, 123);                        \
      acc[m][1] = __builtin_amdgcn_mfma_scale_f32_32x32x64_f8f6f4(         \
          am, b1, acc[m][1], 0, 0, 0, 123, 0, 123);                        \
    }                                                                      \
    __syncthreads();                                                       \
  } while (0)

  STAGE(0, 0);
  __syncthreads();  // tile 0 resident

#pragma unroll 1
  for (int ktp = 0; ktp < 8; ++ktp) {
    BODY(0, 2 * ktp,     true);        // stages 2*ktp+1 -> buf1
    BODY(1, 2 * ktp + 1, (ktp < 7));   // stages 2*ktp+2 -> buf0
  }
#undef STAGE
#undef BODY

  // ---- epilogue: fused softmax stats per 64-col wave chunk ----
  // C/D 32x32 layout: col = lane&31, row = (reg&3) + 8*(reg>>2) + 4*(lane>>5)
  const int chunk = bn * 2 + wn;
  const int colbase = bn * 128 + wn * 64;
  float bov0 = bias[colbase + lr];
  float bov1 = bias[colbase + 32 + lr];
#pragma unroll
  for (int m = 0; m < 2; ++m) {
#pragma unroll
    for (int reg = 0; reg < 16; ++reg) {
      int rowg = bm * 128 + wm * 64 + m * 32 + (reg & 3) + 8 * (reg >> 2) + 4 * kb;
      float v0 = acc[m][0][reg] + bov0;
      float v1 = acc[m][1][reg] + bov1;
      float mv = fmaxf(v0, v1);
#pragma unroll
      for (int sft = 1; sft < 32; sft <<= 1) mv = fmaxf(mv, __shfl_xor(mv, sft));
      float se = __expf(v0 - mv) + __expf(v1 - mv);
#pragma unroll
      for (int sft = 1; sft < 32; sft <<= 1) se += __shfl_xor(se, sft);
      if (lr == 0) {
        pmax[(size_t)rowg * PSTRIDE + chunk] = mv;
        psum[(size_t)rowg * PSTRIDE + chunk] = se;
      }
      int cw = target[rowg] - colbase;
      if (cw >= 0 && cw < 64 && lr == (cw & 31)) {
        tlog[rowg] = (cw < 32) ? v0 : v1;
      }
    }
  }
}

// ---------------- combine per-chunk stats -> nll per row ----------------
__global__ void k_reduce_nll(const float* __restrict__ pmax,
                             const float* __restrict__ psum,
                             const float* __restrict__ tlog,
                             float* __restrict__ nll) {
  int row = blockIdx.x;
  int lane = threadIdx.x; // 64
  float M = -1e30f;
  for (int ch = lane; ch < NCHUNK; ch += 64) M = fmaxf(M, pmax[(size_t)row * PSTRIDE + ch]);
#pragma unroll
  for (int s = 1; s < 64; s <<= 1) M = fmaxf(M, __shfl_xor(M, s));
  float L = 0.f;
  for (int ch = lane; ch < NCHUNK; ch += 64)
    L += __expf(pmax[(size_t)row * PSTRIDE + ch] - M) * psum[(size_t)row * PSTRIDE + ch];
#pragma unroll
  for (int s = 1; s < 64; s <<= 1) L += __shfl_xor(L, s);
  if (lane == 0) nll[row] = -(tlog[row] - M - logf(L));
}

// ---------------- masked per-step mean -> scalar loss ----------------
__global__ void k_loss(const int* __restrict__ target,
                       const float* __restrict__ nll,
                       float* __restrict__ out) {
  __shared__ float red[SS];
  int s = threadIdx.x; // 512
  float sl = 0.f, cnt = 0.f;
#pragma unroll
  for (int b = 0; b < NB; ++b) {
    int idx = b * SS + s;
    if (target[idx] != 0) { sl += nll[idx]; cnt += 1.f; }
  }
  red[s] = sl / fmaxf(cnt, 1.f);
  __syncthreads();
  for (int st = 256; st > 0; st >>= 1) {
    if (s < st) red[s] += red[s + st];
    __syncthreads();
  }
  if (s == 0) out[0] = red[0] / (float)SS;
}

// ---------------- launch ----------------
extern "C" void kernel_launch(void* const* d_in, const int* in_sizes, int n_in,
                              void* d_out, int out_size, void* d_ws, size_t ws_size,
                              hipStream_t stream) {
  (void)in_sizes; (void)n_in; (void)out_size; (void)ws_size;
  const int*   text   = (const int*)d_in[0];
  const int*   target = (const int*)d_in[1];
  const float* embed  = (const float*)d_in[2];
  const float* W1     = (const float*)d_in[3];
  const float* b1     = (const float*)d_in[4];
  const float* W2     = (const float*)d_in[5];
  const float* b2     = (const float*)d_in[6];
  const float* Wo     = (const float*)d_in[7];
  const float* bo     = (const float*)d_in[8];
  float* out = (float*)d_out;
  char* ws = (char*)d_ws;

  const size_t SZ_E = (size_t)MTOK * KDIM * 2;          // 16.78 MB (bf16)
  unsigned short* E   = (unsigned short*)(ws);
  unsigned short* H1  = (unsigned short*)(ws + SZ_E);
  uint8_t*        H2Q = (uint8_t*)(ws + 2 * SZ_E);      // fp8, 8.39 MB
  char* p = ws + 2 * SZ_E + (size_t)MTOK * KDIM;
  unsigned short* W1t = (unsigned short*)p;  p += (size_t)HID * HID * 2;
  unsigned short* W2t = (unsigned short*)p;  p += (size_t)HID * HID * 2;
  uint8_t*        WoQ = (uint8_t*)p;         p += (size_t)VOCAB * HID;   // fp8, 32.77 MB
  float* tlog = (float*)p;                   p += (size_t)MTOK * 4;
  float* nll  = (float*)p;
  float* pmax = (float*)E;   // E dead after GEMM1
  float* psum = (float*)H1;  // H1 dead after GEMM2

  k_transpose_bf16<<<dim3(HID / 32, HID / 32), 256, 0, stream>>>(W1, W1t, HID, HID);
  k_transpose_bf16<<<dim3(HID / 32, HID / 32), 256, 0, stream>>>(W2, W2t, HID, HID);
  k_transpose_fp8 <<<dim3(VOCAB / 32, HID / 32), 256, 0, stream>>>(Wo, WoQ, HID, VOCAB);
  k_gather_e<<<MTOK, 256, 0, stream>>>(text, embed, E);

  k_gemm_ffn<0><<<dim3(HID / 128, MTOK / 128), 256, 0, stream>>>(E, W1t, b1, (void*)H1, HID);
  k_gemm_ffn<1><<<dim3(HID / 128, MTOK / 128), 256, 0, stream>>>(H1, W2t, b2, (void*)H2Q, HID);

  k_gemm_vocab_mx<<<dim3((MTOK / 128) * (VOCAB / 128)), 256, 0, stream>>>(
      H2Q, WoQ, bo, pmax, psum, tlog, target);

  k_reduce_nll<<<MTOK, 64, 0, stream>>>(pmax, psum, tlog, nll);
  k_loss<<<1, SS, 0, stream>>>(target, nll, out);
}